// Round 1
// baseline (604.963 us; speedup 1.0000x reference)
//
#include <hip/hip_runtime.h>

// GARCH scan: B=64, T=2000, F=257, fp32.
// One thread per (b,f) chain; serial loop over t with software-pipelined
// prefetch (depth 8) to keep HBM loads in flight (only ~1 wave/CU).

#define GB 64
#define GT 2000
#define GF 257
#define GEPS 1e-7f

__global__ __launch_bounds__(64) void garch_kernel(
    const float* __restrict__ in,   // (B, T, 2F)
    const float* __restrict__ Alpha,
    const float* __restrict__ beta,
    const float* __restrict__ gamma,
    const float* __restrict__ eta,
    const float* __restrict__ pi,
    float* __restrict__ out)        // (B, T, F)
{
    const int tid = blockIdx.x * 64 + threadIdx.x;
    if (tid >= GB * GF) return;
    const int b = tid / GF;
    const int f = tid - b * GF;

    const float a  = Alpha[f];
    const float be = beta[f];
    const float g  = gamma[f];
    const float e  = eta[f];
    const float pw = pi[f];

    const float* __restrict__ pin  = in  + (size_t)b * GT * 2 * GF + f;
    float* __restrict__       pout = out + (size_t)b * GT * GF + f;

    // carry init from t=0 inputs
    const float mag0  = pin[0];
    const float prob0 = pin[GF];
    float si = mag0 * (1.0f - prob0);
    si = si * si;
    float s0 = si, s1 = si;

    const int S2 = 2 * GF;
    constexpr int UN = 8;          // prefetch depth: 16 loads in flight
    float magb[UN], pb[UN];

    #pragma unroll
    for (int j = 0; j < UN; ++j) {
        magb[j] = pin[(size_t)j * S2];
        pb[j]   = pin[(size_t)j * S2 + GF];
    }

    for (int t0 = 0; t0 < GT; t0 += UN) {
        float magn[UN], pn[UN];
        if (t0 + UN < GT) {
            const float* __restrict__ q = pin + (size_t)(t0 + UN) * S2;
            #pragma unroll
            for (int j = 0; j < UN; ++j) {
                magn[j] = q[(size_t)j * S2];
                pn[j]   = q[(size_t)j * S2 + GF];
            }
        }
        #pragma unroll
        for (int j = 0; j < UN; ++j) {
            const float mag = magb[j];
            const float p   = pb[j];
            const float mag_sq = mag * mag;
            const float noisy =
                (a * s0 + (1.0f - a) * mag_sq) * (1.0f - p)
              + (be + g * s1 + e * s0) * p;
            float c = mag - sqrtf(noisy + GEPS);
            c = fmaxf(c, 0.0f);
            const float ce = fmaxf(mag_sq - pw * c * c, 0.0f);
            s0 = noisy;
            s1 = ce;
            pout[(size_t)(t0 + j) * GF] = c;
        }
        #pragma unroll
        for (int j = 0; j < UN; ++j) { magb[j] = magn[j]; pb[j] = pn[j]; }
    }
}

extern "C" void kernel_launch(void* const* d_in, const int* in_sizes, int n_in,
                              void* d_out, int out_size, void* d_ws, size_t ws_size,
                              hipStream_t stream) {
    const float* in    = (const float*)d_in[0];
    const float* Alpha = (const float*)d_in[1];
    const float* beta  = (const float*)d_in[2];
    const float* gamma = (const float*)d_in[3];
    const float* eta   = (const float*)d_in[4];
    const float* pi    = (const float*)d_in[5];
    float* out = (float*)d_out;

    const int nthreads = GB * GF;              // 16448
    const int grid = (nthreads + 63) / 64;     // 257 blocks of 1 wave each
    garch_kernel<<<grid, 64, 0, stream>>>(in, Alpha, beta, gamma, eta, pi, out);
}

// Round 3
// 468.081 us; speedup vs baseline: 1.2924x; 1.2924x over previous
//
#include <hip/hip_runtime.h>

// GARCH scan: B=64, T=2000, F=257, fp32.
// 257 blocks x 256 threads. Each block owns 64 (b,f) chains.
// All 4 waves stream (mag,p) rows for a CH-timestep chunk into
// double-buffered LDS via global_load_lds DMA; wave 0 runs the serial
// recurrence out of LDS with a register-group pipeline.
//
// Why: round-0 (1 wave/CU, register prefetch depth 1 iter) measured
// effective load latency ~2300 cyc -> 2500 cyc exposed stall per 8 steps.
// Here loads are issued a full chunk (~2250 cyc of compute) ahead and by
// 4 waves, decoupled from the serial chain.

#define GB 64
#define GT 2000
#define GF 257
#define GEPS 1e-7f

constexpr int CH   = 50;           // timesteps per LDS chunk
constexpr int NCH  = GT / CH;      // 40 chunks exactly
constexpr int GRP  = 10;           // compute pipeline group (CH % GRP == 0)
constexpr int NGRP = CH / GRP;     // 5
constexpr int S2   = 2 * GF;

__device__ __forceinline__ void gload_lds4(const float* g, float* l) {
    // LDS dest is wave-uniform base; HW scatters lane i to base + 4*i.
    __builtin_amdgcn_global_load_lds(
        (const __attribute__((address_space(1))) void*)g,
        (__attribute__((address_space(3))) void*)l,
        4, 0, 0);
}

__global__ __launch_bounds__(256) void garch_kernel(
    const float* __restrict__ in,   // (B, T, 2F)
    const float* __restrict__ Alpha,
    const float* __restrict__ beta,
    const float* __restrict__ gamma,
    const float* __restrict__ eta,
    const float* __restrict__ pi,
    float* __restrict__ out)        // (B, T, F)
{
    // LDS: per chunk, row t -> [mag(64) | p(64)] = 128 floats (512 B).
    __shared__ float buf[2][CH * 128];

    const int lane = threadIdx.x & 63;
    const int wv   = threadIdx.x >> 6;          // 0..3

    const int chain = blockIdx.x * 64 + lane;   // < 16448 always (257*64)
    const int b = chain / GF;
    const int f = chain - b * GF;

    const float* __restrict__ gbase = in + (size_t)b * GT * S2 + f;

    // Issue DMA loads for chunk k into buf[k&1]. 100 rows/chunk, 25 per wave.
    auto issue_chunk = [&](int k) {
        if (k < NCH) {
            float* dst = &buf[k & 1][0];
            const size_t tofs = (size_t)k * CH;
            #pragma unroll
            for (int i = 0; i < 2 * CH / 4; ++i) {
                const int r    = (i << 2) | wv;      // 0..(2*CH-1)
                const int trow = r >> 1;
                const int isP  = r & 1;
                const float* g = gbase + (tofs + trow) * (size_t)S2 + (isP ? GF : 0);
                float* l = dst + trow * 128 + (isP ? 64 : 0);  // lane-uniform
                gload_lds4(g, l);
            }
        }
    };

    // Per-lane model params (only wave 0 uses them).
    float a = 0.f, be = 0.f, g_ = 0.f, e_ = 0.f, pw = 0.f;
    float* __restrict__ pout = out;
    if (wv == 0) {
        a  = Alpha[f];
        be = beta[f];
        g_ = gamma[f];
        e_ = eta[f];
        pw = pi[f];
        pout = out + (size_t)b * GT * GF + f;
    }

    issue_chunk(0);
    __syncthreads();   // chunk 0 resident

    float s0 = 0.f, s1 = 0.f;

    for (int k = 0; k < NCH; ++k) {
        issue_chunk(k + 1);   // async DMA into the other buffer (vmcnt)

        if (wv == 0) {
            const float* __restrict__ src = &buf[k & 1][0];

            float mc[GRP], pc[GRP];
            #pragma unroll
            for (int j = 0; j < GRP; ++j) {
                mc[j] = src[j * 128 + lane];
                pc[j] = src[j * 128 + 64 + lane];
            }

            if (k == 0) {
                float si = mc[0] * (1.0f - pc[0]);
                si = si * si;
                s0 = si; s1 = si;
            }

            #pragma unroll
            for (int gi = 0; gi < NGRP; ++gi) {
                float mn[GRP], pn[GRP];
                if (gi + 1 < NGRP) {
                    const float* q = src + (gi + 1) * GRP * 128;
                    #pragma unroll
                    for (int j = 0; j < GRP; ++j) {
                        mn[j] = q[j * 128 + lane];
                        pn[j] = q[j * 128 + 64 + lane];
                    }
                }
                #pragma unroll
                for (int j = 0; j < GRP; ++j) {
                    const float mag    = mc[j];
                    const float p      = pc[j];
                    const float mag_sq = mag * mag;
                    const float noisy =
                        (a * s0 + (1.0f - a) * mag_sq) * (1.0f - p)
                      + (be + g_ * s1 + e_ * s0) * p;
                    float c = mag - __builtin_amdgcn_sqrtf(noisy + GEPS);
                    c = fmaxf(c, 0.0f);
                    const float ce = fmaxf(mag_sq - pw * c * c, 0.0f);
                    s0 = noisy;
                    s1 = ce;
                    const int t = k * CH + gi * GRP + j;
                    pout[(size_t)t * GF] = c;
                }
                #pragma unroll
                for (int j = 0; j < GRP; ++j) { mc[j] = mn[j]; pc[j] = pn[j]; }
            }
        }

        __syncthreads();   // drains DMA (vmcnt) -> chunk k+1 resident
    }
}

extern "C" void kernel_launch(void* const* d_in, const int* in_sizes, int n_in,
                              void* d_out, int out_size, void* d_ws, size_t ws_size,
                              hipStream_t stream) {
    const float* in    = (const float*)d_in[0];
    const float* Alpha = (const float*)d_in[1];
    const float* beta  = (const float*)d_in[2];
    const float* gamma = (const float*)d_in[3];
    const float* eta   = (const float*)d_in[4];
    const float* pi    = (const float*)d_in[5];
    float* out = (float*)d_out;

    const int grid = (GB * GF) / 64;   // 257 blocks, 64 chains each
    garch_kernel<<<grid, 256, 0, stream>>>(in, Alpha, beta, gamma, eta, pi, out);
}

// Round 4
// 451.494 us; speedup vs baseline: 1.3399x; 1.0367x over previous
//
#include <hip/hip_runtime.h>

// GARCH scan: B=64, T=2000, F=257, fp32.
// One thread per (b,f) chain, 257 blocks x 64 threads (1 wave/block,
// ~1 wave/CU). Deep register-ring software pipeline: UN=8 rows per
// iteration, RING=5 slots -> 64 loads in flight per wave (vmcnt cap).
//
// Why: round-1's LDS-DMA chunk scheme was capped at 2.25 B/cyc/CU by the
// __syncthreads() vmcnt(0) drain (bursty, one chunk in flight). Round-0
// showed BW scales with per-wave inflight (16 loads -> 1.1 TB/s,
// eff. latency ~2300 cyc). This keeps the pipe continuously full with
// 4x the outstanding loads and no barrier drains.

#define GB 64
#define GT 2000
#define GF 257
#define GEPS 1e-7f

constexpr int S2   = 2 * GF;
constexpr int UN   = 8;            // rows (timesteps) per iteration
constexpr int RING = 5;            // ring depth in iterations
constexpr int NIT  = GT / UN;      // 250, divisible by RING

__global__ __launch_bounds__(64) void garch_kernel(
    const float* __restrict__ in,   // (B, T, 2F)
    const float* __restrict__ Alpha,
    const float* __restrict__ beta,
    const float* __restrict__ gamma,
    const float* __restrict__ eta,
    const float* __restrict__ pi,
    float* __restrict__ out)        // (B, T, F)
{
    const int tid = blockIdx.x * 64 + threadIdx.x;
    if (tid >= GB * GF) return;
    const int b = tid / GF;
    const int f = tid - b * GF;

    const float a  = Alpha[f];
    const float be = beta[f];
    const float g  = gamma[f];
    const float e  = eta[f];
    const float pw = pi[f];

    const float* __restrict__ pin  = in  + (size_t)b * GT * S2 + f;
    float* __restrict__       pout = out + (size_t)b * GT * GF + f;

    // carry init from t=0 inputs
    const float mag0  = pin[0];
    const float prob0 = pin[GF];
    float si = mag0 * (1.0f - prob0);
    si = si * si;
    float s0 = si, s1 = si;

    // Register ring: RING slots of UN rows (mag, p) each.
    float magb[RING][UN], pb[RING][UN];

    // Prologue: fill slots 0..RING-2 (iterations 0..RING-2).
    #pragma unroll
    for (int r = 0; r < RING - 1; ++r) {
        const float* __restrict__ q = pin + (size_t)(r * UN) * S2;
        #pragma unroll
        for (int j = 0; j < UN; ++j) {
            magb[r][j] = q[(size_t)j * S2];
            pb[r][j]   = q[(size_t)j * S2 + GF];
        }
    }

    for (int it0 = 0; it0 < NIT; it0 += RING) {
        #pragma unroll
        for (int k = 0; k < RING; ++k) {
            const int it = it0 + k;               // consuming slot k
            const int pf = it + (RING - 1);       // prefetch this iteration
            constexpr int PS = RING - 1;
            const int pslot = (k + PS) % RING;    // static after unroll

            if (pf < NIT) {                        // wave-uniform branch
                const float* __restrict__ q = pin + (size_t)(pf * UN) * S2;
                #pragma unroll
                for (int j = 0; j < UN; ++j) {
                    magb[pslot][j] = q[(size_t)j * S2];
                    pb[pslot][j]   = q[(size_t)j * S2 + GF];
                }
            }

            #pragma unroll
            for (int j = 0; j < UN; ++j) {
                const float mag    = magb[k][j];
                const float p      = pb[k][j];
                const float mag_sq = mag * mag;
                const float noisy =
                    (a * s0 + (1.0f - a) * mag_sq) * (1.0f - p)
                  + (be + g * s1 + e * s0) * p;
                float c = mag - __builtin_amdgcn_sqrtf(noisy + GEPS);
                c = fmaxf(c, 0.0f);
                const float ce = fmaxf(mag_sq - pw * c * c, 0.0f);
                s0 = noisy;
                s1 = ce;
                pout[(size_t)(it * UN + j) * GF] = c;
            }
        }
    }
}

extern "C" void kernel_launch(void* const* d_in, const int* in_sizes, int n_in,
                              void* d_out, int out_size, void* d_ws, size_t ws_size,
                              hipStream_t stream) {
    const float* in    = (const float*)d_in[0];
    const float* Alpha = (const float*)d_in[1];
    const float* beta  = (const float*)d_in[2];
    const float* gamma = (const float*)d_in[3];
    const float* eta   = (const float*)d_in[4];
    const float* pi    = (const float*)d_in[5];
    float* out = (float*)d_out;

    const int nthreads = GB * GF;              // 16448
    const int grid = (nthreads + 63) / 64;     // 257 blocks, 1 wave each
    garch_kernel<<<grid, 64, 0, stream>>>(in, Alpha, beta, gamma, eta, pi, out);
}